// Round 4
// baseline (40.021 us; speedup 1.0000x reference)
//
#include <hip/hip_runtime.h>
#include <math.h>

#define CI 16
#define CO 32
#define HH 64
#define WW 64
#define KK 3
#define TH 4
#define TW 16
#define HALO_H (TH + 2)
#define HALO_W (TW + 2)
#define NTAP 9
#define REPS 4

// RingConv2d: out[b,co,ho,wo] = atan2( sum sin(x_p - w), sum cos(x_p - w) )
// over (ci,kh,kw), zero-padded x. Padded positions contribute (cos,sin)=(1,0).
// dir_x = conv(cos x, cos w) + conv(sin x, sin w)
// dir_y = conv(sin x, cos w) - conv(cos x, sin w)
//
// R4 = SCALING PROBE: R2's exact structure, but the compute+epilogue phase
// runs REPS times (rep 0 -> d_out, reps 1..3 -> d_ws scratch regions).
// Accumulators init to rep*1e-30f so the compiler cannot CSE the FMA chains
// across reps (it can't prove fp equivalence); LDS reads re-execute per rep
// (inner-loop-variant, not hoistable without full unroll; rep loop is
// unroll 1). dur = (floor + wprep + stage) + REPS * compute ->
// compute = (dur_R4 - dur_R2) / 3. Decision tree in journal.

__global__ __launch_bounds__(256)
void ringconv_wprep(const float* __restrict__ w, float* __restrict__ wtab) {
    int i = blockIdx.x * 256 + threadIdx.x;
    if (i >= CI * CO * NTAP) return;
    int ci  = i / (CO * NTAP);
    int rem = i - ci * (CO * NTAP);
    int co  = rem / NTAP;
    int tap = rem - co * NTAP;
    float s, c;
    __sincosf(w[i], &s, &c);
    int cg = co >> 1, col = co & 1;
    float* dst = wtab + (((cg * CI + ci) * NTAP + tap) << 2) + (col << 1);
    dst[0] = c;
    dst[1] = s;
}

__global__ __launch_bounds__(1024)
void ringconv_main(const float* __restrict__ x,
                   const float* __restrict__ wtab,
                   float* __restrict__ out,
                   float* __restrict__ wsout,
                   int total) {               // total = B*CO*HH*WW
    // (cos x, sin x) input tile with halo: 16*6*18 float2 = 13824 B
    __shared__ float2 xs[CI][HALO_H][HALO_W];

    const int tid = threadIdx.x;
    const int b   = blockIdx.z;
    const int th0 = blockIdx.y * TH;
    const int tw0 = blockIdx.x * TW;

    // --- stage input tile sincos; out-of-bounds (zero-pad) -> (1,0) ---
    for (int i = tid; i < CI * HALO_H * HALO_W; i += 1024) {
        int ci  = i / (HALO_H * HALO_W);
        int rem = i - ci * (HALO_H * HALO_W);
        int rr  = rem / (HALO_W);
        int cc  = rem - rr * HALO_W;
        int h  = th0 + rr - 1;
        int ww = tw0 + cc - 1;
        float xv = 0.0f;
        if (h >= 0 && h < HH && ww >= 0 && ww < WW)
            xv = x[((b * CI + ci) * HH + h) * WW + ww];
        float s, c2;
        __sincosf(xv, &s, &c2);          // xv==0 -> (1,0): correct pad value
        xs[ci][rr][cc] = make_float2(c2, s);
    }
    __syncthreads();

    const int lane = tid & 63;
    const int wid  = tid >> 6;                             // 0..15 co-pair group
    const int cg   = __builtin_amdgcn_readfirstlane(wid);  // force SGPR-uniform
    const int r    = lane >> 4;                            // 0..3  spatial row
    const int c    = lane & 15;                            // 0..15 spatial col

    const float* __restrict__ wt = wtab + cg * (CI * NTAP * 4);

    #pragma unroll 1
    for (int rep = 0; rep < REPS; ++rep) {
        const float tiny = rep * 1e-30f;   // blocks cross-rep CSE; rep0 == 0.0f
        float ax0 = tiny, ay0 = tiny, ax1 = tiny, ay1 = tiny;

        for (int ci = 0; ci < CI; ++ci) {
            #pragma unroll
            for (int kh = 0; kh < KK; ++kh) {
                #pragma unroll
                for (int kw = 0; kw < KK; ++kw) {
                    const float2 p = xs[ci][r + kh][c + kw];   // lane-varying b64
                    const float* w4 = wt + ((ci * NTAP + kh * KK + kw) << 2);
                    const float wc0 = w4[0], ws0 = w4[1];      // wave-uniform
                    const float wc1 = w4[2], ws1 = w4[3];
                    ax0 = fmaf(p.x, wc0, fmaf(p.y,  ws0, ax0));
                    ay0 = fmaf(p.y, wc0, fmaf(p.x, -ws0, ay0));
                    ax1 = fmaf(p.x, wc1, fmaf(p.y,  ws1, ax1));
                    ay1 = fmaf(p.y, wc1, fmaf(p.x, -ws1, ay1));
                }
            }
        }

        float* __restrict__ obase =
            (rep == 0) ? out : (wsout + (size_t)(rep - 1) * (size_t)total);

        const int co0  = cg * 2;
        const int oidx = ((b * CO + co0) * HH + (th0 + r)) * WW + (tw0 + c);
        obase[oidx]           = atan2f(ay0, ax0);
        obase[oidx + HH * WW] = atan2f(ay1, ax1);
    }
}

extern "C" void kernel_launch(void* const* d_in, const int* in_sizes, int n_in,
                              void* d_out, int out_size, void* d_ws, size_t ws_size,
                              hipStream_t stream) {
    const float* x = (const float*)d_in[0];   // (B, 16, 64, 64) fp32
    const float* w = (const float*)d_in[1];   // (1, 16, 32, 1, 1, 3, 3) fp32
    float* out  = (float*)d_out;              // (B, 32, 64, 64) fp32
    float* wtab = (float*)d_ws;               // 36 KB weight sincos table
    // clone-output scratch, after the weight table (offset 64 KB for alignment)
    float* wsout = (float*)((char*)d_ws + 65536);

    const int B = in_sizes[0] / (CI * HH * WW);
    const int total = B * CO * HH * WW;

    ringconv_wprep<<<(CI * CO * NTAP + 255) / 256, 256, 0, stream>>>(w, wtab);

    dim3 grid(WW / TW, HH / TH, B);           // 4 x 16 x 4 = 256 blocks
    ringconv_main<<<grid, 1024, 0, stream>>>(x, wtab, out, wsout, total);
}

// Round 5
// 17.748 us; speedup vs baseline: 2.2550x; 2.2550x over previous
//
#include <hip/hip_runtime.h>
#include <math.h>

#define CI 16
#define CO 32
#define HH 64
#define WW 64
#define KK 3
#define TH 4
#define TW 16
#define HALO_H (TH + 2)
#define HALO_W (TW + 2)
#define NTAP 9

// RingConv2d: out[b,co,ho,wo] = atan2( sum sin(x_p - w), sum cos(x_p - w) )
// over (ci,kh,kw), zero-padded x. Padded positions contribute (cos,sin)=(1,0).
// dir_x = conv(cos x, cos w) + conv(sin x, sin w)
// dir_y = conv(sin x, cos w) - conv(cos x, sin w)
//
// R5: SINGLE dispatch (R4 probe showed ~12 us of the 19 is non-compute;
// the separate wprep dispatch was part of it). Weight sincos computed
// per-block into LDS (4.5 sincos/thread, hidden under x staging).
// Inner loop is PURE LDS: 1 wave-uniform ds_read_b128 (weight float4,
// broadcast) + 1 lane-varying ds_read_b64 (x) per 8 FMAs. DS returns
// in-order -> compiler can emit fine-grained lgkmcnt(N) instead of the
// full drains forced by R2/R4's out-of-order s_load+ds_read mix (the
// measured 7.0 us vs 3.84 us VALU-floor gap).

__global__ __launch_bounds__(1024)
void ringconv_fused(const float* __restrict__ x,
                    const float* __restrict__ w,
                    float* __restrict__ out) {
    // weight sincos: [cg][ci][tap] = (wc0, ws0, wc1, ws1)  -> 36864 B
    __shared__ __align__(16) float wlds[CO / 2][CI][NTAP][4];
    // x sincos tile with halo: 16*6*18 float2 -> 13824 B
    __shared__ float2 xs[CI][HALO_H][HALO_W];

    const int tid = threadIdx.x;
    const int b   = blockIdx.z;
    const int th0 = blockIdx.y * TH;
    const int tw0 = blockIdx.x * TW;

    // --- stage weight sincos (block-redundant, tiny) ---
    // w flat layout: ci*CO*NTAP + co*NTAP + tap
    for (int i = tid; i < CI * CO * NTAP; i += 1024) {
        int ci  = i / (CO * NTAP);
        int rem = i - ci * (CO * NTAP);
        int co  = rem / NTAP;
        int tap = rem - co * NTAP;
        float s, c;
        __sincosf(w[i], &s, &c);
        float* dst = &wlds[co >> 1][ci][tap][(co & 1) << 1];
        dst[0] = c;
        dst[1] = s;
    }

    // --- stage input tile sincos; out-of-bounds (zero-pad) -> (1,0) ---
    for (int i = tid; i < CI * HALO_H * HALO_W; i += 1024) {
        int ci  = i / (HALO_H * HALO_W);
        int rem = i - ci * (HALO_H * HALO_W);
        int rr  = rem / HALO_W;
        int cc  = rem - rr * HALO_W;
        int h  = th0 + rr - 1;
        int ww = tw0 + cc - 1;
        float xv = 0.0f;
        if (h >= 0 && h < HH && ww >= 0 && ww < WW)
            xv = x[((b * CI + ci) * HH + h) * WW + ww];
        float s, c2;
        __sincosf(xv, &s, &c2);          // xv==0 -> (1,0): correct pad value
        xs[ci][rr][cc] = make_float2(c2, s);
    }
    __syncthreads();

    const int lane = tid & 63;
    const int cg   = tid >> 6;           // 0..15 co-pair group (wave-uniform)
    const int r    = lane >> 4;          // 0..3  spatial row
    const int c    = lane & 15;          // 0..15 spatial col

    float ax0 = 0.f, ay0 = 0.f, ax1 = 0.f, ay1 = 0.f;

    #pragma unroll 2
    for (int ci = 0; ci < CI; ++ci) {
        #pragma unroll
        for (int kh = 0; kh < KK; ++kh) {
            #pragma unroll
            for (int kw = 0; kw < KK; ++kw) {
                const float2 p  = xs[ci][r + kh][c + kw];   // lane-varying b64
                const float4 w4 =                            // uniform b128 (broadcast)
                    *(const float4*)&wlds[cg][ci][kh * KK + kw][0];
                ax0 = fmaf(p.x, w4.x, fmaf(p.y,  w4.y, ax0));
                ay0 = fmaf(p.y, w4.x, fmaf(p.x, -w4.y, ay0));
                ax1 = fmaf(p.x, w4.z, fmaf(p.y,  w4.w, ax1));
                ay1 = fmaf(p.y, w4.z, fmaf(p.x, -w4.w, ay1));
            }
        }
    }

    const int co0  = cg * 2;
    const int oidx = ((b * CO + co0) * HH + (th0 + r)) * WW + (tw0 + c);
    out[oidx]           = atan2f(ay0, ax0);
    out[oidx + HH * WW] = atan2f(ay1, ax1);
}

extern "C" void kernel_launch(void* const* d_in, const int* in_sizes, int n_in,
                              void* d_out, int out_size, void* d_ws, size_t ws_size,
                              hipStream_t stream) {
    const float* x = (const float*)d_in[0];   // (B, 16, 64, 64) fp32
    const float* w = (const float*)d_in[1];   // (1, 16, 32, 1, 1, 3, 3) fp32
    float* out = (float*)d_out;               // (B, 32, 64, 64) fp32

    const int B = in_sizes[0] / (CI * HH * WW);
    dim3 grid(WW / TW, HH / TH, B);           // 4 x 16 x 4 = 256 blocks
    ringconv_fused<<<grid, 1024, 0, stream>>>(x, w, out);
}

// Round 6
// 17.364 us; speedup vs baseline: 2.3049x; 1.0221x over previous
//
#include <hip/hip_runtime.h>
#include <math.h>

#define CI 16
#define CO 32
#define HH 64
#define WW 64
#define KK 3
#define TH 4
#define TW 16
#define HALO_H (TH + 2)
#define HALO_W (TW + 2)
#define NTAP 9

// RingConv2d: out[b,co,ho,wo] = atan2( sum sin(x_p - w), sum cos(x_p - w) )
// over (ci,kh,kw), zero-padded x. Padded positions contribute (cos,sin)=(1,0).
// dir_x = conv(cos x, cos w) + conv(sin x, sin w)
// dir_y = conv(sin x, cos w) - conv(cos x, sin w)
//
// R6: the compute loop is LDS-READ-bound (R4 probe: 7.0 us vs 3.84 us VALU
// floor; per-CU lane-varying x ds_reads were 1.18 MB ~ 4.4 us at 112 B/cy).
// Fix: 4 co per thread (co-quad) -> each x ds_read_b64 feeds 16 FMAs,
// halving per-CU x LDS traffic to 590 KB (~2.2 us < VALU floor). Weights
// come as 2 wave-uniform ds_read_b128 broadcasts per tap (bank-free).
// 512 threads/block (64 spatial pos x 8 co-quads), 256 blocks, 2 waves/SIMD.

__global__ __launch_bounds__(512)
void ringconv_fused(const float* __restrict__ x,
                    const float* __restrict__ w,
                    float* __restrict__ out) {
    // weight sincos: [cq][ci][tap][8] = wc0,ws0,wc1,ws1,wc2,ws2,wc3,ws3
    __shared__ __align__(16) float wlds[CO / 4][CI][NTAP][8];   // 36864 B
    // x sincos tile with halo: 16*6*18 float2 -> 13824 B
    __shared__ float2 xs[CI][HALO_H][HALO_W];

    const int tid = threadIdx.x;          // 0..511
    const int b   = blockIdx.z;
    const int th0 = blockIdx.y * TH;
    const int tw0 = blockIdx.x * TW;

    // --- stage weight sincos (block-redundant, tiny) ---
    // w flat layout: ci*CO*NTAP + co*NTAP + tap
    for (int i = tid; i < CI * CO * NTAP; i += 512) {
        int ci  = i / (CO * NTAP);
        int rem = i - ci * (CO * NTAP);
        int co  = rem / NTAP;
        int tap = rem - co * NTAP;
        float s, c;
        __sincosf(w[i], &s, &c);
        float* dst = &wlds[co >> 2][ci][tap][(co & 3) << 1];
        dst[0] = c;
        dst[1] = s;
    }

    // --- stage input tile sincos; out-of-bounds (zero-pad) -> (1,0) ---
    for (int i = tid; i < CI * HALO_H * HALO_W; i += 512) {
        int ci  = i / (HALO_H * HALO_W);
        int rem = i - ci * (HALO_H * HALO_W);
        int rr  = rem / HALO_W;
        int cc  = rem - rr * HALO_W;
        int h  = th0 + rr - 1;
        int ww = tw0 + cc - 1;
        float xv = 0.0f;
        if (h >= 0 && h < HH && ww >= 0 && ww < WW)
            xv = x[((b * CI + ci) * HH + h) * WW + ww];
        float s, c2;
        __sincosf(xv, &s, &c2);          // xv==0 -> (1,0): correct pad value
        xs[ci][rr][cc] = make_float2(c2, s);
    }
    __syncthreads();

    const int lane = tid & 63;
    const int cq   = __builtin_amdgcn_readfirstlane(tid >> 6); // 0..7 co-quad
    const int r    = lane >> 4;          // 0..3  spatial row
    const int c    = lane & 15;          // 0..15 spatial col

    float ax0 = 0.f, ay0 = 0.f, ax1 = 0.f, ay1 = 0.f;
    float ax2 = 0.f, ay2 = 0.f, ax3 = 0.f, ay3 = 0.f;

    #pragma unroll 2
    for (int ci = 0; ci < CI; ++ci) {
        #pragma unroll
        for (int kh = 0; kh < KK; ++kh) {
            #pragma unroll
            for (int kw = 0; kw < KK; ++kw) {
                const float2 p  = xs[ci][r + kh][c + kw];   // lane-varying b64
                const int tap = kh * KK + kw;
                const float4 wA =                            // uniform b128
                    *(const float4*)&wlds[cq][ci][tap][0];
                const float4 wB =                            // uniform b128
                    *(const float4*)&wlds[cq][ci][tap][4];
                ax0 = fmaf(p.x, wA.x, fmaf(p.y,  wA.y, ax0));
                ay0 = fmaf(p.y, wA.x, fmaf(p.x, -wA.y, ay0));
                ax1 = fmaf(p.x, wA.z, fmaf(p.y,  wA.w, ax1));
                ay1 = fmaf(p.y, wA.z, fmaf(p.x, -wA.w, ay1));
                ax2 = fmaf(p.x, wB.x, fmaf(p.y,  wB.y, ax2));
                ay2 = fmaf(p.y, wB.x, fmaf(p.x, -wB.y, ay2));
                ax3 = fmaf(p.x, wB.z, fmaf(p.y,  wB.w, ax3));
                ay3 = fmaf(p.y, wB.z, fmaf(p.x, -wB.w, ay3));
            }
        }
    }

    const int co0  = cq * 4;
    const int oidx = ((b * CO + co0) * HH + (th0 + r)) * WW + (tw0 + c);
    out[oidx]               = atan2f(ay0, ax0);
    out[oidx + 1 * HH * WW] = atan2f(ay1, ax1);
    out[oidx + 2 * HH * WW] = atan2f(ay2, ax2);
    out[oidx + 3 * HH * WW] = atan2f(ay3, ax3);
}

extern "C" void kernel_launch(void* const* d_in, const int* in_sizes, int n_in,
                              void* d_out, int out_size, void* d_ws, size_t ws_size,
                              hipStream_t stream) {
    const float* x = (const float*)d_in[0];   // (B, 16, 64, 64) fp32
    const float* w = (const float*)d_in[1];   // (1, 16, 32, 1, 1, 3, 3) fp32
    float* out = (float*)d_out;               // (B, 32, 64, 64) fp32

    const int B = in_sizes[0] / (CI * HH * WW);
    dim3 grid(WW / TW, HH / TH, B);           // 4 x 16 x 4 = 256 blocks
    ringconv_fused<<<grid, 512, 0, stream>>>(x, w, out);
}